// Round 6
// baseline (96.253 us; speedup 1.0000x reference)
//
#include <hip/hip_runtime.h>
#include <math.h>

// DSQ (differentiable soft quantization), single-range, n=256 levels, l=-1.
// Pure elementwise map over 67.1M fp32 elements.
// R1: 4x unrolled independent 16B loads (MLP). R2: ext_vector_type.
// R3: cached loads -> input ~50% L3-resident across graph replays (105->88us).
//     FETCH == exactly half input, deterministic -> write stream ALSO
//     allocates in LLC (footprint 512MiB over 256MiB, random repl -> 50%).
// R4: NT-load split was bit-identical neutral -> builtin 'nt' is a no-op for
//     Infinity Cache allocation on gfx950.
// R5: stores via inline asm global_store_dwordx4 sc0 sc1 nt (full scope +
//     non-temporal combo) attempting true LLC bypass so the 256MiB input can
//     become fully resident. Loads plain cached.

typedef float f32x4 __attribute__((ext_vector_type(4)));

__device__ __forceinline__ void st_bypass(f32x4* p, f32x4 v) {
    asm volatile("global_store_dwordx4 %0, %1, off sc0 sc1 nt"
                 :: "v"(p), "v"(v) : "memory");
}

__device__ __forceinline__ float fast_tanh(float y) {
    // tanh(y) = 1 - 2/(exp(2y)+1). |y| <= scale*delta/2 ~ 1.5 here.
    float e = __expf(2.0f * y);
    return 1.0f - 2.0f * __builtin_amdgcn_rcpf(e + 1.0f);
}

struct DsqParams {
    float inv_delta, delta, scale, amp, u;
};

__device__ __forceinline__ float dsq_one(float x, const DsqParams& p) {
    const float l = -1.0f;
    float xc  = fminf(fmaxf(x, l), p.u);                       // clip
    float fi  = fminf(fmaxf(ceilf((x - l) * p.inv_delta - 0.5f), 0.0f), 255.0f);
    float mi  = l + (fi + 0.5f) * p.delta;                     // bin midpoint
    float xsq = p.amp * fast_tanh(p.scale * (xc - mi));
    return l + p.delta * (fi + (xsq + 1.0f) * 0.5f);
}

__device__ __forceinline__ f32x4 dsq_vec4(f32x4 v, const DsqParams& p) {
    f32x4 r;
    r.x = dsq_one(v.x, p);
    r.y = dsq_one(v.y, p);
    r.z = dsq_one(v.z, p);
    r.w = dsq_one(v.w, p);
    return r;
}

__global__ __launch_bounds__(256) void dsq_kernel(
    const float* __restrict__ xx,
    const float* __restrict__ kp,
    const float* __restrict__ up,
    float* __restrict__ out,
    int n4, int n)
{
    const float k = kp[0];
    const float u = up[0];
    DsqParams p;
    p.u = u;
    p.delta = (u - (-1.0f)) * (1.0f / 255.0f);
    p.inv_delta = 1.0f / p.delta;
    p.scale = logf(2.0f / k - 1.0f) * p.inv_delta;
    p.amp = 1.0f / (1.0f - k);

    const f32x4* __restrict__ in4 = (const f32x4*)xx;
    f32x4* __restrict__ out4 = (f32x4*)out;

    const int tid = blockIdx.x * blockDim.x + threadIdx.x;
    const int nth = gridDim.x * blockDim.x;

    constexpr int U = 4;
    const int chunk = nth * U;
    const int nfull = (n4 / chunk) * chunk;

    for (int base = tid; base < nfull; base += chunk) {
        f32x4 v0 = in4[base + 0 * nth];     // cached: L3 retains the input
        f32x4 v1 = in4[base + 1 * nth];
        f32x4 v2 = in4[base + 2 * nth];
        f32x4 v3 = in4[base + 3 * nth];
        f32x4 r0 = dsq_vec4(v0, p);
        f32x4 r1 = dsq_vec4(v1, p);
        f32x4 r2 = dsq_vec4(v2, p);
        f32x4 r3 = dsq_vec4(v3, p);
        st_bypass(&out4[base + 0 * nth], r0);
        st_bypass(&out4[base + 1 * nth], r1);
        st_bypass(&out4[base + 2 * nth], r2);
        st_bypass(&out4[base + 3 * nth], r3);
    }

    // Generic float4 tail (covers n4 not divisible by chunk).
    for (int i4 = nfull + tid; i4 < n4; i4 += nth) {
        f32x4 v = in4[i4];
        f32x4 r = dsq_vec4(v, p);
        st_bypass(&out4[i4], r);
    }

    // Scalar tail (n % 4 != 0) — not hit for 16384*4096, kept for safety.
    for (int i = n4 * 4 + tid; i < n; i += nth) {
        out[i] = dsq_one(xx[i], p);
    }
}

extern "C" void kernel_launch(void* const* d_in, const int* in_sizes, int n_in,
                              void* d_out, int out_size, void* d_ws, size_t ws_size,
                              hipStream_t stream) {
    const float* xx = (const float*)d_in[0];
    const float* k  = (const float*)d_in[1];
    const float* u  = (const float*)d_in[2];
    float* out = (float*)d_out;

    int n  = in_sizes[0];
    int n4 = n / 4;

    int blocks = (n4 + 255) / 256;
    if (blocks > 2048) blocks = 2048;
    if (blocks < 1) blocks = 1;

    dsq_kernel<<<blocks, 256, 0, stream>>>(xx, k, u, out, n4, n);
}

// Round 7
// 94.585 us; speedup vs baseline: 1.0176x; 1.0176x over previous
//
#include <hip/hip_runtime.h>
#include <math.h>

// DSQ (differentiable soft quantization), single-range, n=256 levels, l=-1.
// Pure elementwise map over 67.1M fp32 elements.
// R1: 4x unrolled independent 16B loads (MLP). R2: ext_vector_type.
// R3: cached loads -> input ~50% L3-resident across graph replays (105->88us).
// R4: NT-load split bit-identical neutral -> builtin 'nt' no-op for LLC alloc.
// R5: asm 'sc0 sc1 nt' stores: FETCH unchanged (no LLC-bypass exists), and
//     the asm path cost +8us. REVERTED. Model: equal-rate read+write streams
//     each own ~half the LLC -> 50% input hits, structural. Fabric-bound:
//     537MB combined traffic @ 6.1 TB/s ~= m13 copy ceiling (6.29).
// R6: R3 config + U=8 unroll (8 independent loads in flight, 64MiB chunks,
//     exactly 4 outer iterations), branch-free. Last throughput push.

typedef float f32x4 __attribute__((ext_vector_type(4)));

__device__ __forceinline__ float fast_tanh(float y) {
    // tanh(y) = 1 - 2/(exp(2y)+1). |y| <= scale*delta/2 ~ 1.5 here.
    float e = __expf(2.0f * y);
    return 1.0f - 2.0f * __builtin_amdgcn_rcpf(e + 1.0f);
}

struct DsqParams {
    float inv_delta, delta, scale, amp, u;
};

__device__ __forceinline__ float dsq_one(float x, const DsqParams& p) {
    const float l = -1.0f;
    float xc  = fminf(fmaxf(x, l), p.u);                       // clip
    float fi  = fminf(fmaxf(ceilf((x - l) * p.inv_delta - 0.5f), 0.0f), 255.0f);
    float mi  = l + (fi + 0.5f) * p.delta;                     // bin midpoint
    float xsq = p.amp * fast_tanh(p.scale * (xc - mi));
    return l + p.delta * (fi + (xsq + 1.0f) * 0.5f);
}

__device__ __forceinline__ f32x4 dsq_vec4(f32x4 v, const DsqParams& p) {
    f32x4 r;
    r.x = dsq_one(v.x, p);
    r.y = dsq_one(v.y, p);
    r.z = dsq_one(v.z, p);
    r.w = dsq_one(v.w, p);
    return r;
}

__global__ __launch_bounds__(256) void dsq_kernel(
    const float* __restrict__ xx,
    const float* __restrict__ kp,
    const float* __restrict__ up,
    float* __restrict__ out,
    int n4, int n)
{
    const float k = kp[0];
    const float u = up[0];
    DsqParams p;
    p.u = u;
    p.delta = (u - (-1.0f)) * (1.0f / 255.0f);
    p.inv_delta = 1.0f / p.delta;
    p.scale = logf(2.0f / k - 1.0f) * p.inv_delta;
    p.amp = 1.0f / (1.0f - k);

    const f32x4* __restrict__ in4 = (const f32x4*)xx;
    f32x4* __restrict__ out4 = (f32x4*)out;

    const int tid = blockIdx.x * blockDim.x + threadIdx.x;
    const int nth = gridDim.x * blockDim.x;

    constexpr int U = 8;
    const int chunk = nth * U;
    const int nfull = (n4 / chunk) * chunk;

    for (int base = tid; base < nfull; base += chunk) {
        f32x4 v[U];
        #pragma unroll
        for (int j = 0; j < U; ++j) v[j] = in4[base + j * nth];  // cached
        f32x4 r[U];
        #pragma unroll
        for (int j = 0; j < U; ++j) r[j] = dsq_vec4(v[j], p);
        #pragma unroll
        for (int j = 0; j < U; ++j)
            __builtin_nontemporal_store(r[j], &out4[base + j * nth]);
    }

    // Generic float4 tail (covers n4 not divisible by chunk).
    for (int i4 = nfull + tid; i4 < n4; i4 += nth) {
        f32x4 v = in4[i4];
        f32x4 r = dsq_vec4(v, p);
        __builtin_nontemporal_store(r, &out4[i4]);
    }

    // Scalar tail (n % 4 != 0) — not hit for 16384*4096, kept for safety.
    for (int i = n4 * 4 + tid; i < n; i += nth) {
        out[i] = dsq_one(xx[i], p);
    }
}

extern "C" void kernel_launch(void* const* d_in, const int* in_sizes, int n_in,
                              void* d_out, int out_size, void* d_ws, size_t ws_size,
                              hipStream_t stream) {
    const float* xx = (const float*)d_in[0];
    const float* k  = (const float*)d_in[1];
    const float* u  = (const float*)d_in[2];
    float* out = (float*)d_out;

    int n  = in_sizes[0];
    int n4 = n / 4;

    int blocks = (n4 + 255) / 256;
    if (blocks > 2048) blocks = 2048;
    if (blocks < 1) blocks = 1;

    dsq_kernel<<<blocks, 256, 0, stream>>>(xx, k, u, out, n4, n);
}

// Round 8
// 89.119 us; speedup vs baseline: 1.0801x; 1.0613x over previous
//
#include <hip/hip_runtime.h>
#include <math.h>

// DSQ (differentiable soft quantization), single-range, n=256 levels, l=-1.
// Pure elementwise map over 67.1M fp32 elements.
// R1: 4x unrolled independent 16B loads (MLP). R2: ext_vector_type.
// R3: cached loads -> input ~50% L3-resident across graph replays (105->88us).
// R4: NT-load split bit-identical neutral -> builtin 'nt' no-op for LLC alloc.
// R5: asm 'sc0 sc1 nt' stores regressed (+8us), FETCH unchanged -> no LLC
//     write-bypass exists on gfx950. Structural 50% read-hit (rate-based
//     LLC split between read and write streams).
// R6: U=8 regressed (94.6us): VGPR 32->52, occupancy 58->37%. No latency
//     slack — U=4 is the TLP/ILP balance point.
// R7: exact revert to R3 (best: 87.8us = 6.1 TB/s combined fabric, 97% of
//     the 6.29 TB/s measured mixed-stream ceiling).

typedef float f32x4 __attribute__((ext_vector_type(4)));

__device__ __forceinline__ float fast_tanh(float y) {
    // tanh(y) = 1 - 2/(exp(2y)+1). |y| <= scale*delta/2 ~ 1.5 here.
    float e = __expf(2.0f * y);
    return 1.0f - 2.0f * __builtin_amdgcn_rcpf(e + 1.0f);
}

struct DsqParams {
    float inv_delta, delta, scale, amp, u;
};

__device__ __forceinline__ float dsq_one(float x, const DsqParams& p) {
    const float l = -1.0f;
    float xc  = fminf(fmaxf(x, l), p.u);                       // clip
    float fi  = fminf(fmaxf(ceilf((x - l) * p.inv_delta - 0.5f), 0.0f), 255.0f);
    float mi  = l + (fi + 0.5f) * p.delta;                     // bin midpoint
    float xsq = p.amp * fast_tanh(p.scale * (xc - mi));
    return l + p.delta * (fi + (xsq + 1.0f) * 0.5f);
}

__device__ __forceinline__ f32x4 dsq_vec4(f32x4 v, const DsqParams& p) {
    f32x4 r;
    r.x = dsq_one(v.x, p);
    r.y = dsq_one(v.y, p);
    r.z = dsq_one(v.z, p);
    r.w = dsq_one(v.w, p);
    return r;
}

__global__ __launch_bounds__(256) void dsq_kernel(
    const float* __restrict__ xx,
    const float* __restrict__ kp,
    const float* __restrict__ up,
    float* __restrict__ out,
    int n4, int n)
{
    const float k = kp[0];
    const float u = up[0];
    DsqParams p;
    p.u = u;
    p.delta = (u - (-1.0f)) * (1.0f / 255.0f);
    p.inv_delta = 1.0f / p.delta;
    p.scale = logf(2.0f / k - 1.0f) * p.inv_delta;
    p.amp = 1.0f / (1.0f - k);

    const f32x4* __restrict__ in4 = (const f32x4*)xx;
    f32x4* __restrict__ out4 = (f32x4*)out;

    const int tid = blockIdx.x * blockDim.x + threadIdx.x;
    const int nth = gridDim.x * blockDim.x;

    constexpr int U = 4;
    const int chunk = nth * U;
    const int nfull = (n4 / chunk) * chunk;

    for (int base = tid; base < nfull; base += chunk) {
        f32x4 v0 = in4[base + 0 * nth];     // cached: L3 retains the input
        f32x4 v1 = in4[base + 1 * nth];
        f32x4 v2 = in4[base + 2 * nth];
        f32x4 v3 = in4[base + 3 * nth];
        f32x4 r0 = dsq_vec4(v0, p);
        f32x4 r1 = dsq_vec4(v1, p);
        f32x4 r2 = dsq_vec4(v2, p);
        f32x4 r3 = dsq_vec4(v3, p);
        __builtin_nontemporal_store(r0, &out4[base + 0 * nth]);
        __builtin_nontemporal_store(r1, &out4[base + 1 * nth]);
        __builtin_nontemporal_store(r2, &out4[base + 2 * nth]);
        __builtin_nontemporal_store(r3, &out4[base + 3 * nth]);
    }

    // Generic float4 tail (covers n4 not divisible by chunk).
    for (int i4 = nfull + tid; i4 < n4; i4 += nth) {
        f32x4 v = in4[i4];
        f32x4 r = dsq_vec4(v, p);
        __builtin_nontemporal_store(r, &out4[i4]);
    }

    // Scalar tail (n % 4 != 0) — not hit for 16384*4096, kept for safety.
    for (int i = n4 * 4 + tid; i < n; i += nth) {
        out[i] = dsq_one(xx[i], p);
    }
}

extern "C" void kernel_launch(void* const* d_in, const int* in_sizes, int n_in,
                              void* d_out, int out_size, void* d_ws, size_t ws_size,
                              hipStream_t stream) {
    const float* xx = (const float*)d_in[0];
    const float* k  = (const float*)d_in[1];
    const float* u  = (const float*)d_in[2];
    float* out = (float*)d_out;

    int n  = in_sizes[0];
    int n4 = n / 4;

    int blocks = (n4 + 255) / 256;
    if (blocks > 2048) blocks = 2048;
    if (blocks < 1) blocks = 1;

    dsq_kernel<<<blocks, 256, 0, stream>>>(xx, k, u, out, n4, n);
}